// Round 3
// baseline (271.878 us; speedup 1.0000x reference)
//
#include <hip/hip_runtime.h>
#include <math.h>

#define NN 4096
#define LN_EPS 1e-5f
#define EPS 1e-8f

typedef unsigned short ushortT;
typedef unsigned int uintT;
typedef __attribute__((ext_vector_type(8))) short short8;
typedef __attribute__((ext_vector_type(4))) float f32x4;
typedef __attribute__((ext_vector_type(4))) unsigned short us4;

// workspace offsets (in floats)
// xnF: bf16 A-frags of LN(x)  [b][c=64][frag=8][lane=64][j=8] = 16.78M ushorts (32 MB)
#define OFF_XN    0L
#define OFF_QT    33554432L   // q' bf16 B-frags [b][kb=2][lane64][j8]  65536 us (128KB)
#define OFF_ACC   33587200L   // t [b][k][f] f32            32768
#define OFF_COL   33619968L   // colsum [b][k] f32          512
#define OFF_SLOTS 33620480L   // slots [b][k][d] f32        32768
#define OFF_WIHT  33653248L   // w_ih^T [64][192]           12288
#define OFF_WHHT  33665536L   // w_hh^T [64][192]           12288
#define OFF_W1T   33677824L   // mlp_w1^T [64][128]         8192
#define OFF_W2T   33686016L   // mlp_w2^T [128][64]         8192
#define OFF_WQT   33694208L   // Wq^T [64][64]              4096
#define OFF_WVT   33698304L   // Wv^T [f][d]                4096
#define OFF_CNT   33702400L   // uint cnt[64] per-batch completion counters

__device__ __forceinline__ float wredsum(float v) {
#pragma unroll
  for (int off = 32; off > 0; off >>= 1) v += __shfl_xor(v, off);
  return v;
}

__device__ __forceinline__ ushortT f2bf(float f) {
  uintT b = __float_as_uint(f);
  b += 0x7fff + ((b >> 16) & 1);          // RNE
  return (ushortT)(b >> 16);
}

// ---------------------------------------------------------------------------
// K0: weight prep + zero per-batch counters. (wpack removed; wvT added.)
__global__ __launch_bounds__(256) void k_prep(
    const float* __restrict__ w_ih, const float* __restrict__ w_hh,
    const float* __restrict__ w1, const float* __restrict__ w2,
    const float* __restrict__ Wq, const float* __restrict__ Wv,
    float* __restrict__ wihT, float* __restrict__ whhT,
    float* __restrict__ w1T, float* __restrict__ w2T, float* __restrict__ wqT,
    float* __restrict__ wvT, uintT* __restrict__ cnt)
{
  int idx = blockIdx.x * 256 + threadIdx.x;
  if (idx < 12288) {
    int j = idx >> 6, f = idx & 63;
    wihT[f * 192 + j] = w_ih[idx];
  } else if (idx < 24576) {
    int i = idx - 12288; int j = i >> 6, f = i & 63;
    whhT[f * 192 + j] = w_hh[i];
  } else if (idx < 32768) {
    int i = idx - 24576; int j = i >> 6, f = i & 63;
    w1T[f * 128 + j] = w1[i];
  } else if (idx < 40960) {
    int i = idx - 32768; int d = i >> 7, j = i & 127;
    w2T[j * 64 + d] = w2[i];
  } else if (idx < 45056) {
    int i = idx - 40960; int e = i >> 6, d = i & 63;
    wqT[d * 64 + e] = Wq[i];
  } else if (idx < 49152) {
    int i = idx - 45056; int d = i >> 6, f = i & 63;
    wvT[f * 64 + d] = Wv[i];         // wvT[f][d] = Wv[d][f]
  } else if (idx < 49216) {
    cnt[idx - 49152] = 0u;
  }
}

// ---------------------------------------------------------------------------
// K1: LayerNorm -> xn bf16 A-frags (blocks 0..4095); slot init + q' (4096..4223).
// No projection MFMA anymore: K/V are folded into q' (Wk^T q) and the updater
// (t @ Wv^T), so only xn (32 MB) is materialized. R2 post-mortem: K+V = 64 MB
// was 2x the aggregate L2; k_attn was latency-bound on the L3 path.
__global__ __launch_bounds__(256) void k_ln_init(
    const float* __restrict__ inp,
    const float* __restrict__ g, const float* __restrict__ bbv,
    ushortT* __restrict__ xnG,
    const float* __restrict__ noise, const float* __restrict__ smu,
    const float* __restrict__ slsig, const float* __restrict__ wqT,
    const float* __restrict__ Wk,
    const float* __restrict__ g_sl, const float* __restrict__ b_sl,
    float* __restrict__ slots, ushortT* __restrict__ qF,
    float* __restrict__ acc, float* __restrict__ colsum)
{
  __shared__ __align__(16) ushortT xnF[4096];   // [frag8][lane64][j8]
  const int tid = threadIdx.x;
  const int lane = tid & 63;
  const int wave = tid >> 6;

  if (blockIdx.x >= 4096) {
    // ---- slot init branch ----
    const int bi = blockIdx.x - 4096;
    const int row = bi * 4 + wave;               // 0..511
    const int b = row >> 3, ks = row & 7;
    float* SI = (float*)&xnF[0];                 // 2048 floats; per-wave 512
    float* Sw = SI + (wave << 9);

    float s0 = fmaf(expf(slsig[lane]), noise[row * 64 + lane], smu[lane]);
    slots[row * 64 + lane] = s0;
    acc[row * 64 + lane] = 0.f;
    if (lane == 0) colsum[row] = 0.f;

    float mu = wredsum(s0) * (1.f / 64.f);
    float dx = s0 - mu;
    float var = wredsum(dx * dx) * (1.f / 64.f);
    float sn = dx * rsqrtf(var + LN_EPS) * g_sl[lane] + b_sl[lane];
    Sw[lane] = sn;
    float qe = 0.f;
#pragma unroll 16
    for (int d = 0; d < 64; ++d) qe = fmaf(Sw[d], wqT[d * 64 + lane], qe);
    Sw[64 + lane] = qe;
    float qp = 0.f;
#pragma unroll 16
    for (int e = 0; e < 64; ++e) qp = fmaf(Sw[64 + e], Wk[e * 64 + lane], qp);
    // lane = f. B-frag: kb=f>>5, lrow=(f&31)>>3, j=f&7, col=ks (zero col 8+ks)
    const int kb = lane >> 5, lrow = (lane & 31) >> 3, j = lane & 7;
    qF[((((b * 2 + kb) << 6) + (lrow << 4) + ks) << 3) + j] = f2bf(qp * 0.125f);
    qF[((((b * 2 + kb) << 6) + (lrow << 4) + 8 + ks) << 3) + j] = 0;
    return;
  }

  // ---- LN branch ----
  const int l15 = lane & 15, q = lane >> 4;
  const int tile = blockIdx.x;
  const int b = tile >> 6;
  const int c = tile & 63;
  const int n0 = c << 6;
  const float* rowbase = inp + (((long)b * NN + n0) << 6);
  const float4 g4 = *(const float4*)&g[l15 << 2];
  const float4 b4 = *(const float4*)&bbv[l15 << 2];

#pragma unroll
  for (int i = 0; i < 4; ++i) {
    const int row = (wave << 4) + (i << 2) + q;
    float4 x = *(const float4*)&rowbase[(row << 6) + (l15 << 2)];
    float s = x.x + x.y + x.z + x.w;
    s += __shfl_xor(s, 1); s += __shfl_xor(s, 2);
    s += __shfl_xor(s, 4); s += __shfl_xor(s, 8);
    const float mu = s * (1.f / 64.f);
    float4 dx = {x.x - mu, x.y - mu, x.z - mu, x.w - mu};
    float ss = dx.x * dx.x + dx.y * dx.y + dx.z * dx.z + dx.w * dx.w;
    ss += __shfl_xor(ss, 1); ss += __shfl_xor(ss, 2);
    ss += __shfl_xor(ss, 4); ss += __shfl_xor(ss, 8);
    const float rs = rsqrtf(ss * (1.f / 64.f) + LN_EPS);
    us4 p = {f2bf(dx.x * rs * g4.x + b4.x), f2bf(dx.y * rs * g4.y + b4.y),
             f2bf(dx.z * rs * g4.z + b4.z), f2bf(dx.w * rs * g4.w + b4.w)};
    // A-frag coords: n=row, f=l15*4..+3 -> frag=wave*2+(l15>>3),
    // lane'=((l15&7)>>1)*16+(row&15), j0=(l15&1)*4
    *(us4*)&xnF[((((wave << 1) + (l15 >> 3)) << 6) + (((l15 & 7) >> 1) << 4)
                 + (row & 15)) * 8 + ((l15 & 1) << 2)] = p;
  }
  __syncthreads();

  ushortT* dst = xnG + ((long)(b * 64 + c) << 12);
  short8 v0 = *(const short8*)&xnF[tid << 4];
  short8 v1 = *(const short8*)&xnF[(tid << 4) + 8];
  *(short8*)&dst[tid << 4] = v0;
  *(short8*)&dst[(tid << 4) + 8] = v1;
}

// ---------------------------------------------------------------------------
// K2: fused attention + slot update, single-copy xn.
// QK: A = xn A-frags, B = q' frag (contracts f). PV needs contraction over n,
// so the wave transposes its xn frags through LDS (64 ds_write_b16 with XOR
// granule swizzle -> conflict-light, 8 ds_read_b128) into B-frags, and PV
// produces t = attn^T @ xn; the updater applies Wv in f32.
// LDS: one 32 KB buffer, per-wave 8 KB region phased:
//   phase A: xT (full 8 KB)  phase B: attnF [0..1023], accLds [1024..2047],
//   colLds [2048..2063]      updater: S = floats [0..511].
__global__ __launch_bounds__(256, 4) void k_attn(
    const ushortT* __restrict__ xnG,
    ushortT* __restrict__ qF,
    float* __restrict__ acc, float* __restrict__ colsum,
    uintT* __restrict__ cnt, float* __restrict__ slots,
    const float* __restrict__ wihT, const float* __restrict__ whhT,
    const float* __restrict__ w1T, const float* __restrict__ w2T,
    const float* __restrict__ wqT, const float* __restrict__ Wk,
    const float* __restrict__ wvT,
    const float* __restrict__ b_ih, const float* __restrict__ b_hh,
    const float* __restrict__ mb1, const float* __restrict__ mb2,
    const float* __restrict__ g_ml, const float* __restrict__ b_ml,
    const float* __restrict__ g_sl, const float* __restrict__ b_sl,
    float* __restrict__ dout)
{
  __shared__ __align__(16) ushortT XW[4][4096];
  __shared__ int lastFlag;
  const int tid = threadIdx.x;
  const int lane = tid & 63;
  const int wave = tid >> 6;
  const int l15 = lane & 15, q = lane >> 4;
  const int b = blockIdx.x >> 4;
  const int chunk = ((blockIdx.x & 15) << 2) | wave;  // 0..63

  ushortT* xT = &XW[wave][0];

  const ushortT* kbF = xnG + ((long)(b * 64 + chunk) << 12);

  short8 kA[4][2];
#pragma unroll
  for (int mt = 0; mt < 4; ++mt)
#pragma unroll
    for (int kb = 0; kb < 2; ++kb)
      kA[mt][kb] = *(const short8*)&kbF[((mt * 2 + kb) * 64 + lane) << 3];
  short8 qB[2];
#pragma unroll
  for (int kb = 0; kb < 2; ++kb)
    qB[kb] = *(const short8*)&qF[(((b * 2 + kb) << 6) + lane) << 3];

  f32x4 accL[4];
#pragma unroll
  for (int mt = 0; mt < 4; ++mt) {
    accL[mt] = (f32x4){0.f, 0.f, 0.f, 0.f};
    accL[mt] = __builtin_amdgcn_mfma_f32_16x16x32_bf16(kA[mt][0], qB[0], accL[mt], 0, 0, 0);
    accL[mt] = __builtin_amdgcn_mfma_f32_16x16x32_bf16(kA[mt][1], qB[1], accL[mt], 0, 0, 0);
  }

  // ---- in-LDS transpose: xn A-frags (j-axis=f) -> B-frags (j-axis=n) ----
  // element (l,j) of kA[mt][kb]: n=mt*16+(l&15), f=kb*32+(l>>4)*8+j
  // target frag=(kb*2+(l>>5))*2+(mt>>1); l'=((l>>4)&1)*8+j+(mt&1)*32+((l&15)>>3)*16;
  // j'=l&7. XOR-swizzle 16B granule index with h (else all lanes hit one
  // bank-quad: ~16-way conflict).
  {
    const int h = ((lane >> 5) << 2) | (((lane & 15) >> 3) << 1) | ((lane >> 4) & 1);
    const int jp = lane & 7;
    const int lpA = (((lane >> 4) & 1) << 3) + (((lane & 15) >> 3) << 4);
#pragma unroll
    for (int mt = 0; mt < 4; ++mt)
#pragma unroll
      for (int kb = 0; kb < 2; ++kb) {
        const int fb = (kb * 4 + ((lane >> 5) << 1) + (mt >> 1)) << 9;
        const int lm = lpA + ((mt & 1) << 5);
        const ushortT* src = (const ushortT*)&kA[mt][kb];
#pragma unroll
        for (int j = 0; j < 8; ++j)
          xT[fb + (((lm + j) ^ h) << 3) + jp] = src[j];
      }
  }
  short8 vB[4][2];
#pragma unroll
  for (int nt = 0; nt < 4; ++nt)
#pragma unroll
    for (int ks = 0; ks < 2; ++ks) {
      const int frag = nt * 2 + ks;
      const int hr = ((nt & 1) << 2) | (((lane >> 4) & 1) << 1) | ((lane >> 3) & 1);
      vB[nt][ks] = *(const short8*)&xT[(frag << 9) + ((lane ^ hr) << 3)];
    }

  // softmax over slots (l15 subgroups of 8; cols 8..15 benign: q' cols zeroed)
  ushortT* attnF = &XW[wave][0];     // overwrites xT (vB already in regs)
  float csum = 0.f;
#pragma unroll
  for (int mt = 0; mt < 4; ++mt) {
    float av[4];
#pragma unroll
    for (int r = 0; r < 4; ++r) {
      float lv = accL[mt][r];
      float mx = lv;
      mx = fmaxf(mx, __shfl_xor(mx, 1));
      mx = fmaxf(mx, __shfl_xor(mx, 2));
      mx = fmaxf(mx, __shfl_xor(mx, 4));
      float ev = __expf(lv - mx);
      float sv = ev;
      sv += __shfl_xor(sv, 1); sv += __shfl_xor(sv, 2); sv += __shfl_xor(sv, 4);
      float a = ev * (1.f / sv) + EPS;
      av[r] = a;
      csum += a;
    }
    us4 p = {f2bf(av[0]), f2bf(av[1]), f2bf(av[2]), f2bf(av[3])};
    *(us4*)&attnF[((((mt >> 1) << 6) + (((mt & 1) * 2 + (q >> 1)) << 4)
                    + l15) << 3) + ((q & 1) << 2)] = p;
  }
  csum += __shfl_xor(csum, 16);
  csum += __shfl_xor(csum, 32);

  short8 pA0 = *(const short8*)&attnF[(0 * 64 + lane) << 3];
  short8 pA1 = *(const short8*)&attnF[(1 * 64 + lane) << 3];

  f32x4 accP[4];
#pragma unroll
  for (int nt = 0; nt < 4; ++nt) {
    accP[nt] = (f32x4){0.f, 0.f, 0.f, 0.f};
    accP[nt] = __builtin_amdgcn_mfma_f32_16x16x32_bf16(pA0, vB[nt][0], accP[nt], 0, 0, 0);
    accP[nt] = __builtin_amdgcn_mfma_f32_16x16x32_bf16(pA1, vB[nt][1], accP[nt], 0, 0, 0);
  }

  // C: row k = q*4+r (valid q<2), col f = nt*16 + l15
  float* accLw = (float*)&XW[wave][1024];
  float* colLw = (float*)&XW[wave][2048];
  if (q < 2) {
#pragma unroll
    for (int nt = 0; nt < 4; ++nt)
#pragma unroll
      for (int r = 0; r < 4; ++r)
        accLw[(q * 4 + r) * 64 + nt * 16 + l15] = accP[nt][r];
  }
  if (q == 0 && l15 < 8) colLw[l15] = csum;
  __syncthreads();

#pragma unroll
  for (int r = 0; r < 2; ++r) {
    const int o = tid + r * 256;     // 0..511 -> (k,f)
    const int kk = o >> 6, d = o & 63;
    float s = *((float*)&XW[0][1024] + kk * 64 + d)
            + *((float*)&XW[1][1024] + kk * 64 + d)
            + *((float*)&XW[2][1024] + kk * 64 + d)
            + *((float*)&XW[3][1024] + kk * 64 + d);
    atomicAdd(&acc[(b * 8 + kk) * 64 + d], s);
  }
  if (tid < 8) {
    float s = *((float*)&XW[0][2048] + tid) + *((float*)&XW[1][2048] + tid)
            + *((float*)&XW[2][2048] + tid) + *((float*)&XW[3][2048] + tid);
    atomicAdd(&colsum[b * 8 + tid], s);
  }

  // ----- completion protocol (no __threadfence; see R1 post-mortem) -----
  __syncthreads();
  if (tid == 0) lastFlag = (atomicAdd(&cnt[b], 1u) == 15u);
  __syncthreads();
  if (!lastFlag) return;

  // ===== fused slot update for batch b: wave w handles rows w and w+4 =====
  const int ks0 = wave, ks1 = wave + 4;
  const int row0 = b * 8 + ks0, row1 = b * 8 + ks1;

  float csv0 = 0.f, csv1 = 0.f;
  if (lane == 0) {
    csv0 = atomicAdd(&colsum[row0], 0.f);
    csv1 = atomicAdd(&colsum[row1], 0.f);
  }
  csv0 = __shfl(csv0, 0); csv1 = __shfl(csv1, 0);
  const float t0 = atomicAdd(&acc[row0 * 64 + lane], 0.f) / csv0;
  const float t1 = atomicAdd(&acc[row1 * 64 + lane], 0.f) / csv1;
  const float h0 = slots[row0 * 64 + lane];
  const float h1 = slots[row1 * 64 + lane];

  float* S = (float*)&XW[wave][0];         // 512+ floats, wave-private

  // updates = (t/csum) @ Wv^T  (f32 weights)
  S[256 + lane] = t0; S[320 + lane] = t1;
  float u0 = 0.f, u1 = 0.f;
#pragma unroll 4
  for (int f = 0; f < 64; ++f) {
    const float wv = wvT[f * 64 + lane];
    u0 = fmaf(S[256 + f], wv, u0);
    u1 = fmaf(S[320 + f], wv, u1);
  }

  S[lane] = u0; S[64 + lane] = u1; S[128 + lane] = h0; S[192 + lane] = h1;

  float gir0 = b_ih[lane], giz0 = b_ih[64 + lane], gin0 = b_ih[128 + lane];
  float ghr0 = b_hh[lane], ghz0 = b_hh[64 + lane], ghn0 = b_hh[128 + lane];
  float gir1 = gir0, giz1 = giz0, gin1 = gin0;
  float ghr1 = ghr0, ghz1 = ghz0, ghn1 = ghn0;
#pragma unroll 4
  for (int f = 0; f < 64; ++f) {
    const float wr = wihT[f * 192 + lane], wz = wihT[f * 192 + 64 + lane],
                wn = wihT[f * 192 + 128 + lane];
    const float vr = whhT[f * 192 + lane], vz = whhT[f * 192 + 64 + lane],
                vn = whhT[f * 192 + 128 + lane];
    const float a0 = S[f], a1 = S[64 + f], c0 = S[128 + f], c1 = S[192 + f];
    gir0 = fmaf(a0, wr, gir0); gir1 = fmaf(a1, wr, gir1);
    giz0 = fmaf(a0, wz, giz0); giz1 = fmaf(a1, wz, giz1);
    gin0 = fmaf(a0, wn, gin0); gin1 = fmaf(a1, wn, gin1);
    ghr0 = fmaf(c0, vr, ghr0); ghr1 = fmaf(c1, vr, ghr1);
    ghz0 = fmaf(c0, vz, ghz0); ghz1 = fmaf(c1, vz, ghz1);
    ghn0 = fmaf(c0, vn, ghn0); ghn1 = fmaf(c1, vn, ghn1);
  }
  const float r0 = 1.f / (1.f + expf(-(gir0 + ghr0)));
  const float z0 = 1.f / (1.f + expf(-(giz0 + ghz0)));
  const float n0 = tanhf(fmaf(r0, ghn0, gin0));
  const float hn0 = (1.f - z0) * n0 + z0 * h0;
  const float r1 = 1.f / (1.f + expf(-(gir1 + ghr1)));
  const float z1 = 1.f / (1.f + expf(-(giz1 + ghz1)));
  const float n1 = tanhf(fmaf(r1, ghn1, gin1));
  const float hn1 = (1.f - z1) * n1 + z1 * h1;

  // LN (mlp) both rows
  float mu0 = wredsum(hn0) * (1.f / 64.f);
  float dx0 = hn0 - mu0;
  float va0 = wredsum(dx0 * dx0) * (1.f / 64.f);
  const float ln0 = dx0 * rsqrtf(va0 + LN_EPS) * g_ml[lane] + b_ml[lane];
  float mu1 = wredsum(hn1) * (1.f / 64.f);
  float dx1 = hn1 - mu1;
  float va1 = wredsum(dx1 * dx1) * (1.f / 64.f);
  const float ln1 = dx1 * rsqrtf(va1 + LN_EPS) * g_ml[lane] + b_ml[lane];
  S[256 + lane] = ln0; S[320 + lane] = ln1;

  float h1a0 = mb1[lane], h1b0 = mb1[64 + lane];
  float h1a1 = h1a0, h1b1 = h1b0;
#pragma unroll 4
  for (int f = 0; f < 64; ++f) {
    const float wa = w1T[f * 128 + lane], wb = w1T[f * 128 + 64 + lane];
    const float l0 = S[256 + f], l1 = S[320 + f];
    h1a0 = fmaf(l0, wa, h1a0); h1a1 = fmaf(l1, wa, h1a1);
    h1b0 = fmaf(l0, wb, h1b0); h1b1 = fmaf(l1, wb, h1b1);
  }
  h1a0 = fmaxf(h1a0, 0.f); h1b0 = fmaxf(h1b0, 0.f);
  h1a1 = fmaxf(h1a1, 0.f); h1b1 = fmaxf(h1b1, 0.f);
  S[lane] = h1a0; S[64 + lane] = h1b0;
  S[128 + lane] = h1a1; S[192 + lane] = h1b1;

  float o0 = mb2[lane], o1 = mb2[lane];
#pragma unroll 4
  for (int j = 0; j < 128; ++j) {
    const float w2v = w2T[j * 64 + lane];
    o0 = fmaf(S[j], w2v, o0);
    o1 = fmaf(S[128 + j], w2v, o1);
  }
  const float sn0 = hn0 + o0;
  const float sn1 = hn1 + o1;
  slots[row0 * 64 + lane] = sn0;
  slots[row1 * 64 + lane] = sn1;
  if (dout) {
    dout[row0 * 64 + lane] = sn0;
    dout[row1 * 64 + lane] = sn1;
  }

  // next-iteration q' = (LN_slots(snew) @ Wq^T) @ Wk * D^-0.5 -> bf16 B-frag
  float m20 = wredsum(sn0) * (1.f / 64.f);
  float d20 = sn0 - m20;
  float v20 = wredsum(d20 * d20) * (1.f / 64.f);
  const float sq0 = d20 * rsqrtf(v20 + LN_EPS) * g_sl[lane] + b_sl[lane];
  float m21 = wredsum(sn1) * (1.f / 64.f);
  float d21 = sn1 - m21;
  float v21 = wredsum(d21 * d21) * (1.f / 64.f);
  const float sq1 = d21 * rsqrtf(v21 + LN_EPS) * g_sl[lane] + b_sl[lane];
  S[256 + lane] = sq0; S[320 + lane] = sq1;
  float qe0 = 0.f, qe1 = 0.f;
#pragma unroll 8
  for (int d = 0; d < 64; ++d) {
    const float wq = wqT[d * 64 + lane];
    qe0 = fmaf(S[256 + d], wq, qe0);
    qe1 = fmaf(S[320 + d], wq, qe1);
  }
  S[384 + lane] = qe0; S[448 + lane] = qe1;
  float qp0 = 0.f, qp1 = 0.f;
#pragma unroll 8
  for (int e = 0; e < 64; ++e) {
    const float wk = Wk[e * 64 + lane];
    qp0 = fmaf(S[384 + e], wk, qp0);
    qp1 = fmaf(S[448 + e], wk, qp1);
  }
  const int kb = lane >> 5, lrow = (lane & 31) >> 3, jj = lane & 7;
  qF[((((b * 2 + kb) << 6) + (lrow << 4) + ks0) << 3) + jj] = f2bf(qp0 * 0.125f);
  qF[((((b * 2 + kb) << 6) + (lrow << 4) + ks1) << 3) + jj] = f2bf(qp1 * 0.125f);

  // re-arm for the next k_attn launch
  acc[row0 * 64 + lane] = 0.f;
  acc[row1 * 64 + lane] = 0.f;
  if (lane == 0) { colsum[row0] = 0.f; colsum[row1] = 0.f; }
  if (tid == 0) cnt[b] = 0u;
}

// ---------------------------------------------------------------------------
extern "C" void kernel_launch(void* const* d_in, const int* in_sizes, int n_in,
                              void* d_out, int out_size, void* d_ws, size_t ws_size,
                              hipStream_t stream) {
  const float* inp   = (const float*)d_in[0];
  const float* noise = (const float*)d_in[1];
  const float* smu   = (const float*)d_in[2];
  const float* slsig = (const float*)d_in[3];
  const float* Wq    = (const float*)d_in[4];
  const float* Wk    = (const float*)d_in[5];
  const float* Wv    = (const float*)d_in[6];
  const float* w_ih  = (const float*)d_in[7];
  const float* w_hh  = (const float*)d_in[8];
  const float* b_ih  = (const float*)d_in[9];
  const float* b_hh  = (const float*)d_in[10];
  const float* w1    = (const float*)d_in[11];
  const float* b1    = (const float*)d_in[12];
  const float* w2    = (const float*)d_in[13];
  const float* b2    = (const float*)d_in[14];
  const float* g_in  = (const float*)d_in[15];
  const float* bi_in = (const float*)d_in[16];
  const float* g_sl  = (const float*)d_in[17];
  const float* bi_sl = (const float*)d_in[18];
  const float* g_ml  = (const float*)d_in[19];
  const float* bi_ml = (const float*)d_in[20];

  float* ws      = (float*)d_ws;
  ushortT* xnG   = (ushortT*)(ws + OFF_XN);
  ushortT* qF    = (ushortT*)(ws + OFF_QT);
  float* ac      = ws + OFF_ACC;
  float* cs      = ws + OFF_COL;
  float* sl      = ws + OFF_SLOTS;
  float* wihT    = ws + OFF_WIHT;
  float* whhT    = ws + OFF_WHHT;
  float* w1T     = ws + OFF_W1T;
  float* w2T     = ws + OFF_W2T;
  float* wqT     = ws + OFF_WQT;
  float* wvT     = ws + OFF_WVT;
  uintT* cnt     = (uintT*)(ws + OFF_CNT);

  k_prep<<<193, 256, 0, stream>>>(w_ih, w_hh, w1, w2, Wq, Wv,
                                  wihT, whhT, w1T, w2T, wqT, wvT, cnt);
  k_ln_init<<<4224, 256, 0, stream>>>(inp, g_in, bi_in, xnG,
                                      noise, smu, slsig, wqT, Wk, g_sl, bi_sl,
                                      sl, qF, ac, cs);
  for (int it = 0; it < 3; ++it) {
    k_attn<<<1024, 256, 0, stream>>>(xnG, qF, ac, cs, cnt, sl,
                                     wihT, whhT, w1T, w2T, wqT, Wk, wvT,
                                     b_ih, b_hh, b1, b2, g_ml, bi_ml, g_sl, bi_sl,
                                     it == 2 ? (float*)d_out : nullptr);
  }
}

// Round 4
// 255.710 us; speedup vs baseline: 1.0632x; 1.0632x over previous
//
#include <hip/hip_runtime.h>
#include <math.h>

#define NN 4096
#define LN_EPS 1e-5f
#define EPS 1e-8f

typedef unsigned short ushortT;
typedef unsigned int uintT;
typedef __attribute__((ext_vector_type(8))) short short8;
typedef __attribute__((ext_vector_type(4))) float f32x4;
typedef __attribute__((ext_vector_type(4))) unsigned short us4;

// workspace offsets (in floats)
// xnF: bf16 A-frags of LN(x)  [b][c=64][frag=8][lane=64][j=8] = 16.78M ushorts (32 MB)
#define OFF_XN    0L
#define OFF_QT    33554432L   // q' bf16 B-frags [b][kb=2][lane64][j8]  65536 us (128KB)
#define OFF_ACC   33587200L   // t [b][k][f] f32            32768
#define OFF_COL   33619968L   // colsum [b][k] f32          512
#define OFF_SLOTS 33620480L   // slots [b][k][d] f32        32768
#define OFF_WIHT  33653248L   // w_ih^T [64][192]           12288
#define OFF_WHHT  33665536L   // w_hh^T [64][192]           12288
#define OFF_W1T   33677824L   // mlp_w1^T [64][128]         8192
#define OFF_W2T   33686016L   // mlp_w2^T [128][64]         8192
#define OFF_WQT   33694208L   // Wq^T [64][64]              4096
#define OFF_WVT   33698304L   // Wv^T [f][d]                4096
#define OFF_CNT   33702400L   // uint cnt[64] per-batch completion counters

__device__ __forceinline__ float wredsum(float v) {
#pragma unroll
  for (int off = 32; off > 0; off >>= 1) v += __shfl_xor(v, off);
  return v;
}

__device__ __forceinline__ ushortT f2bf(float f) {
  uintT b = __float_as_uint(f);
  b += 0x7fff + ((b >> 16) & 1);          // RNE
  return (ushortT)(b >> 16);
}

// ---------------------------------------------------------------------------
// K0: weight prep + zero per-batch counters.
__global__ __launch_bounds__(256) void k_prep(
    const float* __restrict__ w_ih, const float* __restrict__ w_hh,
    const float* __restrict__ w1, const float* __restrict__ w2,
    const float* __restrict__ Wq, const float* __restrict__ Wv,
    float* __restrict__ wihT, float* __restrict__ whhT,
    float* __restrict__ w1T, float* __restrict__ w2T, float* __restrict__ wqT,
    float* __restrict__ wvT, uintT* __restrict__ cnt)
{
  int idx = blockIdx.x * 256 + threadIdx.x;
  if (idx < 12288) {
    int j = idx >> 6, f = idx & 63;
    wihT[f * 192 + j] = w_ih[idx];
  } else if (idx < 24576) {
    int i = idx - 12288; int j = i >> 6, f = i & 63;
    whhT[f * 192 + j] = w_hh[i];
  } else if (idx < 32768) {
    int i = idx - 24576; int j = i >> 6, f = i & 63;
    w1T[f * 128 + j] = w1[i];
  } else if (idx < 40960) {
    int i = idx - 32768; int d = i >> 7, j = i & 127;
    w2T[j * 64 + d] = w2[i];
  } else if (idx < 45056) {
    int i = idx - 40960; int e = i >> 6, d = i & 63;
    wqT[d * 64 + e] = Wq[i];
  } else if (idx < 49152) {
    int i = idx - 45056; int d = i >> 6, f = i & 63;
    wvT[f * 64 + d] = Wv[i];         // wvT[f][d] = Wv[d][f]
  } else if (idx < 49216) {
    cnt[idx - 49152] = 0u;
  }
}

// ---------------------------------------------------------------------------
// K1: LayerNorm -> xn bf16 A-frags (blocks 0..4095); slot init + q' (4096..4223).
__global__ __launch_bounds__(256) void k_ln_init(
    const float* __restrict__ inp,
    const float* __restrict__ g, const float* __restrict__ bbv,
    ushortT* __restrict__ xnG,
    const float* __restrict__ noise, const float* __restrict__ smu,
    const float* __restrict__ slsig, const float* __restrict__ wqT,
    const float* __restrict__ Wk,
    const float* __restrict__ g_sl, const float* __restrict__ b_sl,
    float* __restrict__ slots, ushortT* __restrict__ qF,
    float* __restrict__ acc, float* __restrict__ colsum)
{
  __shared__ __align__(16) ushortT xnF[4096];   // [frag8][lane64][j8]
  const int tid = threadIdx.x;
  const int lane = tid & 63;
  const int wave = tid >> 6;

  if (blockIdx.x >= 4096) {
    // ---- slot init branch ----
    const int bi = blockIdx.x - 4096;
    const int row = bi * 4 + wave;               // 0..511
    const int b = row >> 3, ks = row & 7;
    float* SI = (float*)&xnF[0];                 // 2048 floats; per-wave 512
    float* Sw = SI + (wave << 9);

    float s0 = fmaf(expf(slsig[lane]), noise[row * 64 + lane], smu[lane]);
    slots[row * 64 + lane] = s0;
    acc[row * 64 + lane] = 0.f;
    if (lane == 0) colsum[row] = 0.f;

    float mu = wredsum(s0) * (1.f / 64.f);
    float dx = s0 - mu;
    float var = wredsum(dx * dx) * (1.f / 64.f);
    float sn = dx * rsqrtf(var + LN_EPS) * g_sl[lane] + b_sl[lane];
    Sw[lane] = sn;
    float qe = 0.f;
#pragma unroll 16
    for (int d = 0; d < 64; ++d) qe = fmaf(Sw[d], wqT[d * 64 + lane], qe);
    Sw[64 + lane] = qe;
    float qp = 0.f;
#pragma unroll 16
    for (int e = 0; e < 64; ++e) qp = fmaf(Sw[64 + e], Wk[e * 64 + lane], qp);
    // lane = f. B-frag: kb=f>>5, lrow=(f&31)>>3, j=f&7, col=ks (zero col 8+ks)
    const int kb = lane >> 5, lrow = (lane & 31) >> 3, j = lane & 7;
    qF[((((b * 2 + kb) << 6) + (lrow << 4) + ks) << 3) + j] = f2bf(qp * 0.125f);
    qF[((((b * 2 + kb) << 6) + (lrow << 4) + 8 + ks) << 3) + j] = 0;
    return;
  }

  // ---- LN branch ----
  const int l15 = lane & 15, q = lane >> 4;
  const int tile = blockIdx.x;
  const int b = tile >> 6;
  const int c = tile & 63;
  const int n0 = c << 6;
  const float* rowbase = inp + (((long)b * NN + n0) << 6);
  const float4 g4 = *(const float4*)&g[l15 << 2];
  const float4 b4 = *(const float4*)&bbv[l15 << 2];

#pragma unroll
  for (int i = 0; i < 4; ++i) {
    const int row = (wave << 4) + (i << 2) + q;
    float4 x = *(const float4*)&rowbase[(row << 6) + (l15 << 2)];
    float s = x.x + x.y + x.z + x.w;
    s += __shfl_xor(s, 1); s += __shfl_xor(s, 2);
    s += __shfl_xor(s, 4); s += __shfl_xor(s, 8);
    const float mu = s * (1.f / 64.f);
    float4 dx = {x.x - mu, x.y - mu, x.z - mu, x.w - mu};
    float ss = dx.x * dx.x + dx.y * dx.y + dx.z * dx.z + dx.w * dx.w;
    ss += __shfl_xor(ss, 1); ss += __shfl_xor(ss, 2);
    ss += __shfl_xor(ss, 4); ss += __shfl_xor(ss, 8);
    const float rs = rsqrtf(ss * (1.f / 64.f) + LN_EPS);
    us4 p = {f2bf(dx.x * rs * g4.x + b4.x), f2bf(dx.y * rs * g4.y + b4.y),
             f2bf(dx.z * rs * g4.z + b4.z), f2bf(dx.w * rs * g4.w + b4.w)};
    // A-frag coords: n=row, f=l15*4..+3 -> frag=wave*2+(l15>>3),
    // lane'=((l15&7)>>1)*16+(row&15), j0=(l15&1)*4
    *(us4*)&xnF[((((wave << 1) + (l15 >> 3)) << 6) + (((l15 & 7) >> 1) << 4)
                 + (row & 15)) * 8 + ((l15 & 1) << 2)] = p;
  }
  __syncthreads();

  ushortT* dst = xnG + ((long)(b * 64 + c) << 12);
  short8 v0 = *(const short8*)&xnF[tid << 4];
  short8 v1 = *(const short8*)&xnF[(tid << 4) + 8];
  *(short8*)&dst[tid << 4] = v0;
  *(short8*)&dst[(tid << 4) + 8] = v1;
}

// ---------------------------------------------------------------------------
// K2: fused attention + slot update, MLP-restructured (R3 post-mortem: k_attn
// was latency-bound on its miss stream — dur ~= FETCH/500GB/s with VALUBusy
// <10% in every prior round; loads sat idle while long load-free compute/
// atomic phases ran).
//   - 512 blocks (8/batch, cnt target 7); each wave processes TWO 64-token
//     chunks; all 16 staging loads are issued up front, so chunk 1's fetch
//     latency hides under chunk 0's compute (2x MLP).
//   - PV accumulates both chunks into one C-operand; csum folds once.
//   - atomics + protocol traffic halved vs R3.
// LDS per wave (8 KB region): xT transpose buf / attnF / accLds / updater S.
__global__ __launch_bounds__(256, 2) void k_attn(
    const ushortT* __restrict__ xnG,
    ushortT* __restrict__ qF,
    float* __restrict__ acc, float* __restrict__ colsum,
    uintT* __restrict__ cnt, float* __restrict__ slots,
    const float* __restrict__ wihT, const float* __restrict__ whhT,
    const float* __restrict__ w1T, const float* __restrict__ w2T,
    const float* __restrict__ wqT, const float* __restrict__ Wk,
    const float* __restrict__ wvT,
    const float* __restrict__ b_ih, const float* __restrict__ b_hh,
    const float* __restrict__ mb1, const float* __restrict__ mb2,
    const float* __restrict__ g_ml, const float* __restrict__ b_ml,
    const float* __restrict__ g_sl, const float* __restrict__ b_sl,
    float* __restrict__ dout)
{
  __shared__ __align__(16) ushortT XW[4][4096];
  __shared__ int lastFlag;
  const int tid = threadIdx.x;
  const int lane = tid & 63;
  const int wave = tid >> 6;
  const int l15 = lane & 15, q = lane >> 4;
  const int b = blockIdx.x >> 3;
  const int e = blockIdx.x & 7;        // eighth of the batch

  ushortT* xT = &XW[wave][0];

  // wave's two chunks: e*8 + c*4 + wave, c in {0,1}
  const ushortT* pc0 = xnG + ((long)(b * 64 + (e << 3) + wave) << 12);
  const ushortT* pc1 = pc0 + (4L << 12);

  // issue ALL staging loads up front (16 KB/wave in flight)
  short8 kA0[4][2], kA1[4][2];
#pragma unroll
  for (int mt = 0; mt < 4; ++mt)
#pragma unroll
    for (int kb = 0; kb < 2; ++kb) {
      kA0[mt][kb] = *(const short8*)&pc0[((mt * 2 + kb) * 64 + lane) << 3];
      kA1[mt][kb] = *(const short8*)&pc1[((mt * 2 + kb) * 64 + lane) << 3];
    }
  short8 qB[2];
#pragma unroll
  for (int kb = 0; kb < 2; ++kb)
    qB[kb] = *(const short8*)&qF[(((b * 2 + kb) << 6) + lane) << 3];

  f32x4 accP[4];
#pragma unroll
  for (int nt = 0; nt < 4; ++nt) accP[nt] = (f32x4){0.f, 0.f, 0.f, 0.f};
  float csum = 0.f;

  auto do_chunk = [&](const short8 (&kA)[4][2]) {
    // QK: A = xn frags, B = q' frag (contracts f)
    f32x4 accL[4];
#pragma unroll
    for (int mt = 0; mt < 4; ++mt) {
      accL[mt] = (f32x4){0.f, 0.f, 0.f, 0.f};
      accL[mt] = __builtin_amdgcn_mfma_f32_16x16x32_bf16(kA[mt][0], qB[0], accL[mt], 0, 0, 0);
      accL[mt] = __builtin_amdgcn_mfma_f32_16x16x32_bf16(kA[mt][1], qB[1], accL[mt], 0, 0, 0);
    }

    // in-LDS transpose: xn A-frags (j-axis=f) -> B-frags (j-axis=n)
    {
      const int h = ((lane >> 5) << 2) | (((lane & 15) >> 3) << 1) | ((lane >> 4) & 1);
      const int jp = lane & 7;
      const int lpA = (((lane >> 4) & 1) << 3) + (((lane & 15) >> 3) << 4);
#pragma unroll
      for (int mt = 0; mt < 4; ++mt)
#pragma unroll
        for (int kb = 0; kb < 2; ++kb) {
          const int fb = (kb * 4 + ((lane >> 5) << 1) + (mt >> 1)) << 9;
          const int lm = lpA + ((mt & 1) << 5);
          const ushortT* src = (const ushortT*)&kA[mt][kb];
#pragma unroll
          for (int j = 0; j < 8; ++j)
            xT[fb + (((lm + j) ^ h) << 3) + jp] = src[j];
        }
    }
    short8 vB[4][2];
#pragma unroll
    for (int nt = 0; nt < 4; ++nt)
#pragma unroll
      for (int ks = 0; ks < 2; ++ks) {
        const int frag = nt * 2 + ks;
        const int hr = ((nt & 1) << 2) | (((lane >> 4) & 1) << 1) | ((lane >> 3) & 1);
        vB[nt][ks] = *(const short8*)&xT[(frag << 9) + ((lane ^ hr) << 3)];
      }

    // softmax over slots (cols 8..15 benign: q' cols zeroed)
    ushortT* attnF = &XW[wave][0];   // overwrites xT (vB already in regs)
#pragma unroll
    for (int mt = 0; mt < 4; ++mt) {
      float av[4];
#pragma unroll
      for (int r = 0; r < 4; ++r) {
        float lv = accL[mt][r];
        float mx = lv;
        mx = fmaxf(mx, __shfl_xor(mx, 1));
        mx = fmaxf(mx, __shfl_xor(mx, 2));
        mx = fmaxf(mx, __shfl_xor(mx, 4));
        float ev = __expf(lv - mx);
        float sv = ev;
        sv += __shfl_xor(sv, 1); sv += __shfl_xor(sv, 2); sv += __shfl_xor(sv, 4);
        float a = ev * (1.f / sv) + EPS;
        av[r] = a;
        csum += a;
      }
      us4 p = {f2bf(av[0]), f2bf(av[1]), f2bf(av[2]), f2bf(av[3])};
      *(us4*)&attnF[((((mt >> 1) << 6) + (((mt & 1) * 2 + (q >> 1)) << 4)
                      + l15) << 3) + ((q & 1) << 2)] = p;
    }

    short8 pA0 = *(const short8*)&attnF[(0 * 64 + lane) << 3];
    short8 pA1 = *(const short8*)&attnF[(1 * 64 + lane) << 3];

#pragma unroll
    for (int nt = 0; nt < 4; ++nt) {
      accP[nt] = __builtin_amdgcn_mfma_f32_16x16x32_bf16(pA0, vB[nt][0], accP[nt], 0, 0, 0);
      accP[nt] = __builtin_amdgcn_mfma_f32_16x16x32_bf16(pA1, vB[nt][1], accP[nt], 0, 0, 0);
    }
  };

  do_chunk(kA0);
  do_chunk(kA1);

  // fold csum across q-groups (linear, so once after both chunks)
  csum += __shfl_xor(csum, 16);
  csum += __shfl_xor(csum, 32);

  // C: row k = q*4+r (valid q<2), col f = nt*16 + l15
  float* accLw = (float*)&XW[wave][1024];
  float* colLw = (float*)&XW[wave][2048];
  if (q < 2) {
#pragma unroll
    for (int nt = 0; nt < 4; ++nt)
#pragma unroll
      for (int r = 0; r < 4; ++r)
        accLw[(q * 4 + r) * 64 + nt * 16 + l15] = accP[nt][r];
  }
  if (q == 0 && l15 < 8) colLw[l15] = csum;
  __syncthreads();

#pragma unroll
  for (int r = 0; r < 2; ++r) {
    const int o = tid + r * 256;     // 0..511 -> (k,f)
    const int kk = o >> 6, d = o & 63;
    float s = *((float*)&XW[0][1024] + kk * 64 + d)
            + *((float*)&XW[1][1024] + kk * 64 + d)
            + *((float*)&XW[2][1024] + kk * 64 + d)
            + *((float*)&XW[3][1024] + kk * 64 + d);
    atomicAdd(&acc[(b * 8 + kk) * 64 + d], s);
  }
  if (tid < 8) {
    float s = *((float*)&XW[0][2048] + tid) + *((float*)&XW[1][2048] + tid)
            + *((float*)&XW[2][2048] + tid) + *((float*)&XW[3][2048] + tid);
    atomicAdd(&colsum[b * 8 + tid], s);
  }

  // ----- completion protocol (no __threadfence; see R1 post-mortem) -----
  __syncthreads();
  if (tid == 0) lastFlag = (atomicAdd(&cnt[b], 1u) == 7u);
  __syncthreads();
  if (!lastFlag) return;

  // ===== fused slot update for batch b: wave w handles rows w and w+4 =====
  const int ks0 = wave, ks1 = wave + 4;
  const int row0 = b * 8 + ks0, row1 = b * 8 + ks1;

  float csv0 = 0.f, csv1 = 0.f;
  if (lane == 0) {
    csv0 = atomicAdd(&colsum[row0], 0.f);
    csv1 = atomicAdd(&colsum[row1], 0.f);
  }
  csv0 = __shfl(csv0, 0); csv1 = __shfl(csv1, 0);
  const float t0 = atomicAdd(&acc[row0 * 64 + lane], 0.f) / csv0;
  const float t1 = atomicAdd(&acc[row1 * 64 + lane], 0.f) / csv1;
  const float h0 = slots[row0 * 64 + lane];
  const float h1 = slots[row1 * 64 + lane];

  float* S = (float*)&XW[wave][0];         // 512+ floats, wave-private

  // updates = (t/csum) @ Wv^T  (f32 weights)
  S[256 + lane] = t0; S[320 + lane] = t1;
  float u0 = 0.f, u1 = 0.f;
#pragma unroll 4
  for (int f = 0; f < 64; ++f) {
    const float wv = wvT[f * 64 + lane];
    u0 = fmaf(S[256 + f], wv, u0);
    u1 = fmaf(S[320 + f], wv, u1);
  }

  S[lane] = u0; S[64 + lane] = u1; S[128 + lane] = h0; S[192 + lane] = h1;

  float gir0 = b_ih[lane], giz0 = b_ih[64 + lane], gin0 = b_ih[128 + lane];
  float ghr0 = b_hh[lane], ghz0 = b_hh[64 + lane], ghn0 = b_hh[128 + lane];
  float gir1 = gir0, giz1 = giz0, gin1 = gin0;
  float ghr1 = ghr0, ghz1 = ghz0, ghn1 = ghn0;
#pragma unroll 4
  for (int f = 0; f < 64; ++f) {
    const float wr = wihT[f * 192 + lane], wz = wihT[f * 192 + 64 + lane],
                wn = wihT[f * 192 + 128 + lane];
    const float vr = whhT[f * 192 + lane], vz = whhT[f * 192 + 64 + lane],
                vn = whhT[f * 192 + 128 + lane];
    const float a0 = S[f], a1 = S[64 + f], c0 = S[128 + f], c1 = S[192 + f];
    gir0 = fmaf(a0, wr, gir0); gir1 = fmaf(a1, wr, gir1);
    giz0 = fmaf(a0, wz, giz0); giz1 = fmaf(a1, wz, giz1);
    gin0 = fmaf(a0, wn, gin0); gin1 = fmaf(a1, wn, gin1);
    ghr0 = fmaf(c0, vr, ghr0); ghr1 = fmaf(c1, vr, ghr1);
    ghz0 = fmaf(c0, vz, ghz0); ghz1 = fmaf(c1, vz, ghz1);
    ghn0 = fmaf(c0, vn, ghn0); ghn1 = fmaf(c1, vn, ghn1);
  }
  const float r0 = 1.f / (1.f + expf(-(gir0 + ghr0)));
  const float z0 = 1.f / (1.f + expf(-(giz0 + ghz0)));
  const float n0 = tanhf(fmaf(r0, ghn0, gin0));
  const float hn0 = (1.f - z0) * n0 + z0 * h0;
  const float r1 = 1.f / (1.f + expf(-(gir1 + ghr1)));
  const float z1 = 1.f / (1.f + expf(-(giz1 + ghz1)));
  const float n1 = tanhf(fmaf(r1, ghn1, gin1));
  const float hn1 = (1.f - z1) * n1 + z1 * h1;

  // LN (mlp) both rows
  float mu0 = wredsum(hn0) * (1.f / 64.f);
  float dx0 = hn0 - mu0;
  float va0 = wredsum(dx0 * dx0) * (1.f / 64.f);
  const float ln0 = dx0 * rsqrtf(va0 + LN_EPS) * g_ml[lane] + b_ml[lane];
  float mu1 = wredsum(hn1) * (1.f / 64.f);
  float dx1 = hn1 - mu1;
  float va1 = wredsum(dx1 * dx1) * (1.f / 64.f);
  const float ln1 = dx1 * rsqrtf(va1 + LN_EPS) * g_ml[lane] + b_ml[lane];
  S[256 + lane] = ln0; S[320 + lane] = ln1;

  float h1a0 = mb1[lane], h1b0 = mb1[64 + lane];
  float h1a1 = h1a0, h1b1 = h1b0;
#pragma unroll 4
  for (int f = 0; f < 64; ++f) {
    const float wa = w1T[f * 128 + lane], wb = w1T[f * 128 + 64 + lane];
    const float l0 = S[256 + f], l1 = S[320 + f];
    h1a0 = fmaf(l0, wa, h1a0); h1a1 = fmaf(l1, wa, h1a1);
    h1b0 = fmaf(l0, wb, h1b0); h1b1 = fmaf(l1, wb, h1b1);
  }
  h1a0 = fmaxf(h1a0, 0.f); h1b0 = fmaxf(h1b0, 0.f);
  h1a1 = fmaxf(h1a1, 0.f); h1b1 = fmaxf(h1b1, 0.f);
  S[lane] = h1a0; S[64 + lane] = h1b0;
  S[128 + lane] = h1a1; S[192 + lane] = h1b1;

  float o0 = mb2[lane], o1 = mb2[lane];
#pragma unroll 4
  for (int j = 0; j < 128; ++j) {
    const float w2v = w2T[j * 64 + lane];
    o0 = fmaf(S[j], w2v, o0);
    o1 = fmaf(S[128 + j], w2v, o1);
  }
  const float sn0 = hn0 + o0;
  const float sn1 = hn1 + o1;
  slots[row0 * 64 + lane] = sn0;
  slots[row1 * 64 + lane] = sn1;
  if (dout) {
    dout[row0 * 64 + lane] = sn0;
    dout[row1 * 64 + lane] = sn1;
  }

  // next-iteration q' = (LN_slots(snew) @ Wq^T) @ Wk * D^-0.5 -> bf16 B-frag
  float m20 = wredsum(sn0) * (1.f / 64.f);
  float d20 = sn0 - m20;
  float v20 = wredsum(d20 * d20) * (1.f / 64.f);
  const float sq0 = d20 * rsqrtf(v20 + LN_EPS) * g_sl[lane] + b_sl[lane];
  float m21 = wredsum(sn1) * (1.f / 64.f);
  float d21 = sn1 - m21;
  float v21 = wredsum(d21 * d21) * (1.f / 64.f);
  const float sq1 = d21 * rsqrtf(v21 + LN_EPS) * g_sl[lane] + b_sl[lane];
  S[256 + lane] = sq0; S[320 + lane] = sq1;
  float qe0 = 0.f, qe1 = 0.f;
#pragma unroll 8
  for (int d = 0; d < 64; ++d) {
    const float wq = wqT[d * 64 + lane];
    qe0 = fmaf(S[256 + d], wq, qe0);
    qe1 = fmaf(S[320 + d], wq, qe1);
  }
  S[384 + lane] = qe0; S[448 + lane] = qe1;
  float qp0 = 0.f, qp1 = 0.f;
#pragma unroll 8
  for (int e2 = 0; e2 < 64; ++e2) {
    const float wk = Wk[e2 * 64 + lane];
    qp0 = fmaf(S[384 + e2], wk, qp0);
    qp1 = fmaf(S[448 + e2], wk, qp1);
  }
  const int kb = lane >> 5, lrow = (lane & 31) >> 3, jj = lane & 7;
  qF[((((b * 2 + kb) << 6) + (lrow << 4) + ks0) << 3) + jj] = f2bf(qp0 * 0.125f);
  qF[((((b * 2 + kb) << 6) + (lrow << 4) + ks1) << 3) + jj] = f2bf(qp1 * 0.125f);

  // re-arm for the next k_attn launch
  acc[row0 * 64 + lane] = 0.f;
  acc[row1 * 64 + lane] = 0.f;
  if (lane == 0) { colsum[row0] = 0.f; colsum[row1] = 0.f; }
  if (tid == 0) cnt[b] = 0u;
}

// ---------------------------------------------------------------------------
extern "C" void kernel_launch(void* const* d_in, const int* in_sizes, int n_in,
                              void* d_out, int out_size, void* d_ws, size_t ws_size,
                              hipStream_t stream) {
  const float* inp   = (const float*)d_in[0];
  const float* noise = (const float*)d_in[1];
  const float* smu   = (const float*)d_in[2];
  const float* slsig = (const float*)d_in[3];
  const float* Wq    = (const float*)d_in[4];
  const float* Wk    = (const float*)d_in[5];
  const float* Wv    = (const float*)d_in[6];
  const float* w_ih  = (const float*)d_in[7];
  const float* w_hh  = (const float*)d_in[8];
  const float* b_ih  = (const float*)d_in[9];
  const float* b_hh  = (const float*)d_in[10];
  const float* w1    = (const float*)d_in[11];
  const float* b1    = (const float*)d_in[12];
  const float* w2    = (const float*)d_in[13];
  const float* b2    = (const float*)d_in[14];
  const float* g_in  = (const float*)d_in[15];
  const float* bi_in = (const float*)d_in[16];
  const float* g_sl  = (const float*)d_in[17];
  const float* bi_sl = (const float*)d_in[18];
  const float* g_ml  = (const float*)d_in[19];
  const float* bi_ml = (const float*)d_in[20];

  float* ws      = (float*)d_ws;
  ushortT* xnG   = (ushortT*)(ws + OFF_XN);
  ushortT* qF    = (ushortT*)(ws + OFF_QT);
  float* ac      = ws + OFF_ACC;
  float* cs      = ws + OFF_COL;
  float* sl      = ws + OFF_SLOTS;
  float* wihT    = ws + OFF_WIHT;
  float* whhT    = ws + OFF_WHHT;
  float* w1T     = ws + OFF_W1T;
  float* w2T     = ws + OFF_W2T;
  float* wqT     = ws + OFF_WQT;
  float* wvT     = ws + OFF_WVT;
  uintT* cnt     = (uintT*)(ws + OFF_CNT);

  k_prep<<<193, 256, 0, stream>>>(w_ih, w_hh, w1, w2, Wq, Wv,
                                  wihT, whhT, w1T, w2T, wqT, wvT, cnt);
  k_ln_init<<<4224, 256, 0, stream>>>(inp, g_in, bi_in, xnG,
                                      noise, smu, slsig, wqT, Wk, g_sl, bi_sl,
                                      sl, qF, ac, cs);
  for (int it = 0; it < 3; ++it) {
    k_attn<<<512, 256, 0, stream>>>(xnG, qF, ac, cs, cnt, sl,
                                    wihT, whhT, w1T, w2T, wqT, Wk, wvT,
                                    b_ih, b_hh, b1, b2, g_ml, bi_ml, g_sl, bi_sl,
                                    it == 2 ? (float*)d_out : nullptr);
  }
}